// Round 2
// baseline (15607.005 us; speedup 1.0000x reference)
//
#include <hip/hip_runtime.h>
#include <math.h>

#define B 32
#define T 800
#define DE 512
#define E 256
#define H 512
#define A 512
#define V 10000
#define S 100
#define VP 10016

#define NBLK 256
#define NT 512

// workspace word offsets
#define OFF_BAR    0                    // 512 words (8 counters, 256B apart)
#define OFF_ENCP   512                  // B*T*A = 13107200
#define OFF_XCAT   (OFF_ENCP + B*T*A)       // B*1280
#define OFF_YCAT   (OFF_XCAT + B*1280)      // B*1024
#define OFF_DECC   (OFF_YCAT + B*1024)      // B*512
#define OFF_QV     (OFF_DECC + B*512)       // B*512
#define OFF_EBUF   (OFF_QV + B*512)         // B*800
#define OFF_LP     (OFF_EBUF + B*800)       // B*VP

#define SMW 4096   // weight tile base in LDS words

__device__ __forceinline__ float tanh_fast(float x) {
    float e = __expf(2.0f * x);
    return 1.0f - __fdividef(2.0f, e + 1.0f);
}

struct DecArgs {
    const float* encpad; const float* emb; const float* Wih; const float* Whh;
    const float* bih; const float* bhh; const float* Wdec; const float* vatt;
    const float* Wout; const float* bout; const int* enclen;
    float* outp; float* ws;
};

// enc_proj[25600,512] = enc_pad[25600,512] @ W_enc[512,512]  (once, before coop)
__global__ __launch_bounds__(256) void k_encproj(const float* Ap, const float* Wenc, float* outp) {
    __shared__ float Ast[16][68];
    __shared__ float Bs[16][68];
    int rb = blockIdx.x, cb = blockIdx.y;
    int tid = threadIdx.x;
    int tx = tid & 15, ty = tid >> 4;
    float acc[4][4] = {};
    for (int kb = 0; kb < 32; kb++) {
        #pragma unroll
        for (int i = 0; i < 4; i++) {
            int idx = tid + i*256;
            int r = idx >> 4, k = idx & 15;
            Ast[k][r] = Ap[(rb*64 + r)*512 + kb*16 + k];
        }
        #pragma unroll
        for (int i = 0; i < 4; i++) {
            int idx = tid + i*256;
            int k = idx >> 6, c = idx & 63;
            Bs[k][c] = Wenc[(kb*16 + k)*512 + cb*64 + c];
        }
        __syncthreads();
        #pragma unroll
        for (int kk = 0; kk < 16; kk++) {
            float4 a4 = *(const float4*)&Ast[kk][ty*4];
            float4 b4 = *(const float4*)&Bs[kk][tx*4];
            const float av[4] = {a4.x, a4.y, a4.z, a4.w};
            const float bv[4] = {b4.x, b4.y, b4.z, b4.w};
            #pragma unroll
            for (int i = 0; i < 4; i++)
                #pragma unroll
                for (int j = 0; j < 4; j++)
                    acc[i][j] += av[i] * bv[j];
        }
        __syncthreads();
    }
    #pragma unroll
    for (int i = 0; i < 4; i++)
        #pragma unroll
        for (int j = 0; j < 4; j++)
            outp[(rb*64 + ty*4 + i)*512 + cb*64 + tx*4 + j] = acc[i][j];
}

// grid barrier: 8 spread counters, monotonic target
__device__ __forceinline__ void gsync(unsigned* bars, unsigned target) {
    __syncthreads();
    if (threadIdx.x == 0) {
        __builtin_amdgcn_fence(__ATOMIC_RELEASE, "agent");
        __hip_atomic_fetch_add(&bars[(blockIdx.x & 7) * 64], 1u,
                               __ATOMIC_RELAXED, __HIP_MEMORY_SCOPE_AGENT);
        unsigned sum;
        do {
            sum = 0;
            #pragma unroll
            for (int i = 0; i < 8; i++)
                sum += __hip_atomic_load(&bars[i*64], __ATOMIC_RELAXED, __HIP_MEMORY_SCOPE_AGENT);
            if (sum < target) __builtin_amdgcn_s_sleep(1);
        } while (sum < target);
        __builtin_amdgcn_fence(__ATOMIC_ACQUIRE, "agent");
    }
    __syncthreads();
}

// stage x-operand k-major with quad-XOR swizzle: sm[k*32 + (b ^ ((k>>2 & 7)<<2))]
__device__ __forceinline__ void stage_xs(float* sm, const float* src, int stride, int ks) {
    int k4 = threadIdx.x & 31, bb = threadIdx.x >> 5;
    #pragma unroll
    for (int h = 0; h < 2; h++) {
        int b = bb + 16*h;
        float4 v = *(const float4*)&src[b*stride + ks + 4*k4];
        int sw = (k4 & 7) << 2;
        int idx = (4*k4)*32 + (b ^ sw);
        sm[idx] = v.x; sm[idx+32] = v.y; sm[idx+64] = v.z; sm[idx+96] = v.w;
    }
}

#define XSREAD(smp, k, bq) (*(const float4*)&(smp)[(k)*32 + (((4*(bq)) ^ ((((k)>>2) & 7) << 2)))])

__global__ __launch_bounds__(NT) void coop_decoder(DecArgs a) {
    __shared__ float sm[12608];
    int* smi = (int*)sm;
    const int tid = threadIdx.x;
    const int blk = blockIdx.x;
    unsigned* bars = (unsigned*)a.ws;
    float* xcat = a.ws + OFF_XCAT;
    float* ycat = a.ws + OFF_YCAT;
    float* decc = a.ws + OFF_DECC;
    float* qv   = a.ws + OFF_QV;
    float* ebuf = a.ws + OFF_EBUF;
    float* lp   = a.ws + OFF_LP;
    const float* encp = a.ws + OFF_ENCP;

    unsigned target = NBLK;

    // ---- init: xcat = [emb(BOS) | 0 ctx | 0 z], decc = 0
    if (blk < 32) {
        int b = blk;
        if (tid < 256) xcat[b*1280 + tid] = a.emb[1*E + tid];
        xcat[b*1280 + 256 + tid] = 0.f;
        xcat[b*1280 + 768 + tid] = 0.f;
        decc[b*512 + tid] = 0.f;
    }
    gsync(bars, target); target += NBLK;

    for (int s = 0; s < S; s++) {
        // ================= phase A: gates + LSTM (blocks 0..127, h0=blk*4)
        if (blk < 128) {
            const int h0 = blk*4;
            const int bq = tid & 7, rq = (tid >> 3) & 3, kq = tid >> 5; // 8*4*16
            float acc[4][4] = {};
            for (int ch = 0; ch < 10; ch++) {
                const int ks = ch*128;
                stage_xs(sm, xcat, 1280, ks);
                {   // wt[r][k] row-major pad 133; r=g*4+hl -> j=g*512+h0+hl
                    int k4 = tid & 31, r = tid >> 5;
                    int j = (r >> 2)*512 + h0 + (r & 3);
                    int kk = ks + 4*k4;
                    float4 w = (kk < 768) ? *(const float4*)&a.Wih[j*768 + kk]
                                          : *(const float4*)&a.Whh[j*512 + (kk - 768)];
                    int base = SMW + r*133 + 4*k4;
                    sm[base] = w.x; sm[base+1] = w.y; sm[base+2] = w.z; sm[base+3] = w.w;
                }
                __syncthreads();
                #pragma unroll
                for (int kk = 0; kk < 8; kk++) {
                    int k = kq*8 + kk;
                    float4 xv = XSREAD(sm, k, bq);
                    #pragma unroll
                    for (int i = 0; i < 4; i++) {
                        float w = sm[SMW + (4*rq + i)*133 + k];
                        acc[i][0] += w*xv.x; acc[i][1] += w*xv.y;
                        acc[i][2] += w*xv.z; acc[i][3] += w*xv.w;
                    }
                }
                __syncthreads();
            }
            #pragma unroll
            for (int i = 0; i < 4; i++)
                #pragma unroll
                for (int j = 0; j < 4; j++)
                    sm[kq*528 + (4*rq + i)*33 + (4*bq + j)] = acc[i][j];
            __syncthreads();
            {   // sum 16 kq partials -> gsum[r][b]
                int r = tid >> 5, b = tid & 31;
                float gs = 0.f;
                #pragma unroll
                for (int k2 = 0; k2 < 16; k2++) gs += sm[k2*528 + r*33 + b];
                sm[8448 + r*33 + b] = gs;
            }
            __syncthreads();
            if (tid < 128) {
                int hl = tid >> 5, b = tid & 31;
                int h = h0 + hl;
                float gi = sm[8448 + (0*4+hl)*33 + b] + a.bih[h]        + a.bhh[h];
                float gf = sm[8448 + (1*4+hl)*33 + b] + a.bih[512+h]    + a.bhh[512+h];
                float gg = sm[8448 + (2*4+hl)*33 + b] + a.bih[1024+h]   + a.bhh[1024+h];
                float go = sm[8448 + (3*4+hl)*33 + b] + a.bih[1536+h]   + a.bhh[1536+h];
                float ig = 1.f/(1.f + expf(-gi));
                float fg = 1.f/(1.f + expf(-gf));
                float g2 = tanhf(gg);
                float og = 1.f/(1.f + expf(-go));
                float c = fg*decc[b*512 + h] + ig*g2;
                decc[b*512 + h] = c;
                float z = og*tanhf(c);
                ycat[b*1024 + h] = z;
                xcat[b*1280 + 768 + h] = z;
            }
        }
        gsync(bars, target); target += NBLK;

        // ================= phase B: q = dec_z @ W_dec (blocks 0..31, a0=blk*16)
        if (blk < 32) {
            const int a0 = blk*16;
            const int bq = tid & 7, rq = (tid >> 3) & 3, kq = tid >> 5;
            float acc[4][4] = {};
            for (int ch = 0; ch < 4; ch++) {
                const int ks = ch*128;
                stage_xs(sm, ycat, 1024, ks);   // dec_z region (k<512)
                {   // wdec_s[k][16] k-major (W_dec already k-major)
                    int a4 = tid & 3, k = tid >> 2;
                    float4 w = *(const float4*)&a.Wdec[(ks + k)*512 + a0 + 4*a4];
                    *(float4*)&sm[SMW + k*16 + 4*a4] = w;
                }
                __syncthreads();
                #pragma unroll
                for (int kk = 0; kk < 8; kk++) {
                    int k = kq*8 + kk;
                    float4 xv = XSREAD(sm, k, bq);
                    float4 wv = *(const float4*)&sm[SMW + k*16 + 4*rq];
                    acc[0][0] += wv.x*xv.x; acc[0][1] += wv.x*xv.y; acc[0][2] += wv.x*xv.z; acc[0][3] += wv.x*xv.w;
                    acc[1][0] += wv.y*xv.x; acc[1][1] += wv.y*xv.y; acc[1][2] += wv.y*xv.z; acc[1][3] += wv.y*xv.w;
                    acc[2][0] += wv.z*xv.x; acc[2][1] += wv.z*xv.y; acc[2][2] += wv.z*xv.z; acc[2][3] += wv.z*xv.w;
                    acc[3][0] += wv.w*xv.x; acc[3][1] += wv.w*xv.y; acc[3][2] += wv.w*xv.z; acc[3][3] += wv.w*xv.w;
                }
                __syncthreads();
            }
            #pragma unroll
            for (int i = 0; i < 4; i++)
                #pragma unroll
                for (int j = 0; j < 4; j++)
                    sm[kq*528 + (4*rq + i)*33 + (4*bq + j)] = acc[i][j];
            __syncthreads();
            {
                int r = tid & 15, b = tid >> 4;
                float qs = 0.f;
                #pragma unroll
                for (int k2 = 0; k2 < 16; k2++) qs += sm[k2*528 + r*33 + b];
                qv[b*512 + a0 + r] = qs;
            }
        }
        gsync(bars, target); target += NBLK;

        // ================= phase C: e[b,t] = tanh(encp + q) . v_att  (256 blocks)
        {
            int b = blk >> 3, sl = blk & 7;
            int len = a.enclen[b];
            int t0 = sl*100;
            if (t0 < len) {
                sm[tid] = qv[b*512 + tid];
                sm[512 + tid] = a.vatt[tid];
                __syncthreads();
                int wid = tid >> 6, lane = tid & 63;
                int tend = min(t0 + 100, len);
                for (int t = t0 + wid; t < tend; t += 8) {
                    const float4* row = (const float4*)&encp[(b*800 + t)*512];
                    float accd = 0.f;
                    #pragma unroll
                    for (int i = 0; i < 2; i++) {
                        int u = lane + 64*i;
                        float4 ep = row[u];
                        float4 q4 = *(const float4*)&sm[4*u];
                        float4 vv = *(const float4*)&sm[512 + 4*u];
                        accd += tanh_fast(ep.x + q4.x)*vv.x;
                        accd += tanh_fast(ep.y + q4.y)*vv.y;
                        accd += tanh_fast(ep.z + q4.z)*vv.z;
                        accd += tanh_fast(ep.w + q4.w)*vv.w;
                    }
                    #pragma unroll
                    for (int off = 32; off >= 1; off >>= 1)
                        accd += __shfl_xor(accd, off, 64);
                    if (lane == 0) ebuf[b*800 + t] = accd;
                }
                __syncthreads();
            }
        }
        gsync(bars, target); target += NBLK;

        // ================= phase DE: softmax (replicated) + context (256 blocks: b x d-slice)
        {
            int b = blk >> 3, dsl = blk & 7;
            int len = a.enclen[b];
            int d0 = dsl*64;
            // max
            float m = -3.0e38f;
            for (int t = tid; t < len; t += NT) m = fmaxf(m, ebuf[b*800 + t]);
            sm[1024 + tid] = m;
            __syncthreads();
            for (int st = 256; st >= 1; st >>= 1) {
                if (tid < st) sm[1024 + tid] = fmaxf(sm[1024 + tid], sm[1024 + tid + st]);
                __syncthreads();
            }
            float M = sm[1024];
            __syncthreads();
            // exp -> p_lds, sum
            float ssum = 0.f;
            for (int t = tid; t < len; t += NT) {
                float p = expf(ebuf[b*800 + t] - M);
                sm[t] = p;
                ssum += p;
            }
            sm[1024 + tid] = ssum;
            __syncthreads();
            for (int st = 256; st >= 1; st >>= 1) {
                if (tid < st) sm[1024 + tid] += sm[1024 + tid + st];
                __syncthreads();
            }
            float inv = 1.f / sm[1024];
            // write w output row slice (reuse dsl as t-slice)
            {
                int t0 = dsl*100;
                float* wrow = a.outp + 2*B*S + (size_t)(b*S + s)*T;
                for (int t = t0 + tid; t < t0 + 100; t += NT)
                    wrow[t] = (t < len) ? sm[t]*inv : 0.f;
            }
            // context over full t for this d-slice
            {
                int d = tid & 63, ts = tid >> 6;
                float accd = 0.f;
                for (int t = ts; t < len; t += 8)
                    accd += sm[t] * a.encpad[(b*800 + t)*512 + d0 + d];
                accd *= inv;
                __syncthreads();
                sm[1536 + ts*68 + d] = accd;
                __syncthreads();
                if (tid < 64) {
                    float c = 0.f;
                    #pragma unroll
                    for (int t2 = 0; t2 < 8; t2++) c += sm[1536 + t2*68 + tid];
                    ycat[b*1024 + 512 + d0 + tid] = c;
                    xcat[b*1280 + 256 + d0 + tid] = c;
                }
            }
        }
        gsync(bars, target); target += NBLK;

        // ================= phase F: logits = y @ W_out.T + b_out (blocks 0..156, v0=blk*64)
        if (blk < 157) {
            const int v0 = blk*64;
            const int bq = tid & 7, rq = (tid >> 3) & 15, kq = tid >> 7; // 8*16*4
            float acc[4][4] = {};
            for (int ch = 0; ch < 8; ch++) {
                const int ks = ch*128;
                stage_xs(sm, ycat, 1024, ks);
                {   // wt[r][k] row-major pad 133, r=0..63
                    int k4 = tid & 31, rr = tid >> 5;
                    #pragma unroll
                    for (int h = 0; h < 4; h++) {
                        int r = rr + 16*h;
                        int row = min(v0 + r, V - 1);
                        float4 w = *(const float4*)&a.Wout[(size_t)row*1024 + ks + 4*k4];
                        int base = SMW + r*133 + 4*k4;
                        sm[base] = w.x; sm[base+1] = w.y; sm[base+2] = w.z; sm[base+3] = w.w;
                    }
                }
                __syncthreads();
                #pragma unroll
                for (int kk = 0; kk < 32; kk++) {
                    int k = kq*32 + kk;
                    float4 xv = XSREAD(sm, k, bq);
                    #pragma unroll
                    for (int i = 0; i < 4; i++) {
                        float w = sm[SMW + (4*rq + i)*133 + k];
                        acc[i][0] += w*xv.x; acc[i][1] += w*xv.y;
                        acc[i][2] += w*xv.z; acc[i][3] += w*xv.w;
                    }
                }
                __syncthreads();
            }
            #pragma unroll
            for (int i = 0; i < 4; i++)
                #pragma unroll
                for (int j = 0; j < 4; j++)
                    sm[kq*2112 + (4*rq + i)*33 + (4*bq + j)] = acc[i][j];
            __syncthreads();
            for (int o = tid; o < 2048; o += NT) {
                int r = o & 63, b2 = o >> 6;
                int v = v0 + r;
                if (v < V) {
                    float val = a.bout[v];
                    #pragma unroll
                    for (int k2 = 0; k2 < 4; k2++) val += sm[k2*2112 + r*33 + b2];
                    lp[b2*VP + v] = val;
                }
            }
        }
        gsync(bars, target); target += NBLK;

        // ================= phase G: argmax + log-softmax + emb feedback (blocks 0..31)
        if (blk < 32) {
            int b = blk;
            float lv[20];
            float lmax = -3.0e38f; int lidx = 0x7fffffff;
            #pragma unroll
            for (int it = 0; it < 20; it++) {
                int v = it*NT + tid;
                float x = (v < V) ? lp[b*VP + v] : -3.0e38f;
                lv[it] = x;
                if (x > lmax) { lmax = x; lidx = v; }
            }
            sm[tid] = lmax; smi[512 + tid] = lidx;
            __syncthreads();
            for (int st = 256; st >= 1; st >>= 1) {
                if (tid < st) {
                    float ov = sm[tid + st]; int oi = smi[512 + tid + st];
                    if (ov > sm[tid] || (ov == sm[tid] && oi < smi[512 + tid])) {
                        sm[tid] = ov; smi[512 + tid] = oi;
                    }
                }
                __syncthreads();
            }
            float M = sm[0]; int am = smi[512];
            __syncthreads();
            float ssum = 0.f;
            #pragma unroll
            for (int it = 0; it < 20; it++) ssum += expf(lv[it] - M);
            sm[tid] = ssum;
            __syncthreads();
            for (int st = 256; st >= 1; st >>= 1) {
                if (tid < st) sm[tid] += sm[tid + st];
                __syncthreads();
            }
            if (tid == 0) {
                a.outp[b*S + s] = -logf(sm[0]);
                a.outp[B*S + b*S + s] = (float)am;
            }
            if (tid < 256) xcat[b*1280 + tid] = a.emb[(size_t)am*E + tid];
        }
        gsync(bars, target); target += NBLK;
    }
}

extern "C" void kernel_launch(void* const* d_in, const int* in_sizes, int n_in,
                              void* d_out, int out_size, void* d_ws, size_t ws_size,
                              hipStream_t stream) {
    (void)in_sizes; (void)n_in; (void)out_size; (void)ws_size;
    const float* encpad = (const float*)d_in[0];
    const float* emb    = (const float*)d_in[1];
    const float* Wih    = (const float*)d_in[2];
    const float* Whh    = (const float*)d_in[3];
    const float* bih    = (const float*)d_in[4];
    const float* bhh    = (const float*)d_in[5];
    const float* Wenc   = (const float*)d_in[6];
    const float* Wdec   = (const float*)d_in[7];
    const float* vatt   = (const float*)d_in[8];
    const float* Wout   = (const float*)d_in[9];
    const float* bout   = (const float*)d_in[10];
    const int*   enclen = (const int*)d_in[11];
    float* outp = (float*)d_out;
    float* ws   = (float*)d_ws;

    // zero the barrier counters (first 2 KB of workspace)
    hipMemsetAsync(d_ws, 0, 2048, stream);

    k_encproj<<<dim3(400, 8), 256, 0, stream>>>(encpad, Wenc, ws + OFF_ENCP);

    DecArgs args = { encpad, emb, Wih, Whh, bih, bhh, Wdec, vatt, Wout, bout,
                     enclen, outp, ws };
    void* kp[] = { &args };
    hipLaunchCooperativeKernel((const void*)coop_decoder, dim3(NBLK), dim3(NT),
                               kp, 0, stream);
}